// Round 4
// baseline (203.116 us; speedup 1.0000x reference)
//
#include <hip/hip_runtime.h>
#include <hip/hip_bf16.h>

typedef __bf16 bf16x8 __attribute__((ext_vector_type(8)));
typedef float  f32x4  __attribute__((ext_vector_type(4)));

// freqs[i] = 10000^(-i/16) = 10^(-i/4), i=0..7 (odd k-chunks scale by 1e-2)
__constant__ __device__ const float FREQ8[8] = {
    1.0f, 0.5623413251903491f, 0.31622776601683794f, 0.17782794100389228f,
    0.1f, 0.05623413251903491f, 0.031622776601683794f, 0.017782794100389228f };

// One wave = 64 points. D = W_tile(16e x 32d) * emb^T(32d x 16pt):
//   A-frag = W  (row=lane&15 -> e,     k=8*(lane>>4)+j -> d)
//   B-frag = emb (col=lane&15 -> point, k=8*(lane>>4)+j -> d)
//   D: col=lane&15 -> point, row=(lane>>4)*4+reg -> e  => 4 consecutive e per
//   lane = one 16B dwordx4 store. No LDS anywhere.
template<bool POW2>
__global__ __launch_bounds__(256) void relds_mfma(
    const float* __restrict__ pos,   // [B,N,3]
    const float* __restrict__ tim,   // [B,N]
    const float* __restrict__ W,     // [32,32] row-major W[e][d]
    const float* __restrict__ bias,  // [32]
    float* __restrict__ out_attn,    // f32 [P,32]
    float* __restrict__ out_emb,     // f32 [P,32]
    int N, int NN, int P, int logN)
{
    const int tid  = threadIdx.x;
    const int lane = tid & 63;
    const int wave = tid >> 6;
    const int row  = lane & 15;   // point-slot in B/D cols; e-row for A frag
    const int kb   = lane >> 4;   // k-chunk 0..3; also e-quad for D rows

    // ---- A fragments (W) + bias quads, once per block; L1/L2-resident ----
    bf16x8 Wf[2];
    f32x4  bq[2];
    #pragma unroll
    for (int n = 0; n < 2; ++n) {
        const int e = n * 16 + row;
        const float4 wA = *reinterpret_cast<const float4*>(W + e * 32 + kb * 8);
        const float4 wB = *reinterpret_cast<const float4*>(W + e * 32 + kb * 8 + 4);
        Wf[n][0] = (__bf16)wA.x; Wf[n][1] = (__bf16)wA.y;
        Wf[n][2] = (__bf16)wA.z; Wf[n][3] = (__bf16)wA.w;
        Wf[n][4] = (__bf16)wB.x; Wf[n][5] = (__bf16)wB.y;
        Wf[n][6] = (__bf16)wB.z; Wf[n][7] = (__bf16)wB.w;
        const float4 bb = *reinterpret_cast<const float4*>(bias + n * 16 + kb * 4);
        bq[n][0] = bb.x; bq[n][1] = bb.y; bq[n][2] = bb.z; bq[n][3] = bb.w;
    }

    const int wbase = blockIdx.x * 256 + wave * 64;
    if (wbase >= P) return;

    // lane-uniform angle constants: d = kb*8+j; odd chunk -> freqs*1e-2; kb>=2 -> cos
    constexpr float INV2PI = 0.15915494309189535f;
    const float premul = INV2PI * ((kb & 1) ? 0.01f : 1.0f);
    const float qoff   = (kb >= 2) ? 0.25f : 0.0f;   // cos(z) = sin(z + 1/4 rev)

    f32x4 acc[4][2];
    #pragma unroll
    for (int t = 0; t < 4; ++t)
        #pragma unroll
        for (int n = 0; n < 2; ++n) acc[t][n] = bq[n];

    #pragma unroll
    for (int t = 0; t < 4; ++t) {
        const int q  = wbase + t * 16 + row;
        const int qc = (q < P) ? q : (P - 1);
        int in_n, in_m;
        if (POW2) {
            in_n = qc >> logN;
            in_m = ((qc >> (2 * logN)) << logN) | (qc & (N - 1));
        } else {
            const int b_ = qc / NN; const int r_ = qc - b_ * NN;
            const int n_ = r_ / N;  const int m_ = r_ - n_ * N;
            in_n = b_ * N + n_;     in_m = b_ * N + m_;
        }
        const float dx = pos[in_n * 3 + 0] - pos[in_m * 3 + 0];
        const float dy = pos[in_n * 3 + 1] - pos[in_m * 3 + 1];
        const float dz = pos[in_n * 3 + 2] - pos[in_m * 3 + 2];
        const float dt = (tim[in_n] - tim[in_m]) * 18.0f;  // TIME_SCALE
        const float ds2 = dx * dx + dy * dy + dz * dz - dt * dt;
        const float d   = copysignf(sqrtf(fabsf(ds2)), ds2);
        const float x   = 1024.0f * fminf(4.0f, fmaxf(-4.0f, d));
        const float xr  = x * premul;   // revolutions, pre-scaled per k-chunk

        float v[8];
        #pragma unroll
        for (int j = 0; j < 8; ++j) {
            float rr = fmaf(xr, FREQ8[j], qoff);
            rr -= floorf(rr);
            v[j] = __builtin_amdgcn_sinf(rr);
        }

        if (q < P) {  // emb out: lane owns dims kb*8..kb*8+7 of point q
            float* ep = out_emb + (size_t)q * 32 + kb * 8;
            f32x4 e0 = { v[0], v[1], v[2], v[3] };
            f32x4 e1 = { v[4], v[5], v[6], v[7] };
            __builtin_nontemporal_store(e0, reinterpret_cast<f32x4*>(ep));
            __builtin_nontemporal_store(e1, reinterpret_cast<f32x4*>(ep) + 1);
        }

        bf16x8 Af;
        #pragma unroll
        for (int j = 0; j < 8; ++j) Af[j] = (__bf16)v[j];
        acc[t][0] = __builtin_amdgcn_mfma_f32_16x16x32_bf16(Wf[0], Af, acc[t][0], 0, 0, 0);
        acc[t][1] = __builtin_amdgcn_mfma_f32_16x16x32_bf16(Wf[1], Af, acc[t][1], 0, 0, 0);
    }

    // ---- rel_attn stores: D col=lane&15 -> point, rows = n*16 + kb*4 + r ----
    #pragma unroll
    for (int t = 0; t < 4; ++t) {
        const int q = wbase + t * 16 + row;
        if (q < P) {
            float* ap = out_attn + (size_t)q * 32 + kb * 4;
            __builtin_nontemporal_store(acc[t][0], reinterpret_cast<f32x4*>(ap));
            __builtin_nontemporal_store(acc[t][1], reinterpret_cast<f32x4*>(ap + 16));
        }
    }
}

extern "C" void kernel_launch(void* const* d_in, const int* in_sizes, int n_in,
                              void* d_out, int out_size, void* d_ws, size_t ws_size,
                              hipStream_t stream) {
    const float* pos  = (const float*)d_in[0];
    const float* tim  = (const float*)d_in[1];
    const float* W    = (const float*)d_in[2];
    const float* bias = (const float*)d_in[3];

    const int BN = in_sizes[1];          // B*N
    const int P  = out_size / 64;        // B*N*N
    const int N  = P / BN;
    const int NN = N * N;

    int logN = 0;
    while ((1 << logN) < N) ++logN;
    const bool pow2 = ((1 << logN) == N);

    float* out_attn = (float*)d_out;
    float* out_emb  = out_attn + (size_t)out_size / 2;

    const int grid = (P + 255) / 256;
    if (pow2)
        relds_mfma<true><<<grid, 256, 0, stream>>>(pos, tim, W, bias, out_attn, out_emb, N, NN, P, logN);
    else
        relds_mfma<false><<<grid, 256, 0, stream>>>(pos, tim, W, bias, out_attn, out_emb, N, NN, P, logN);
}

// Round 5
// 109.031 us; speedup vs baseline: 1.8629x; 1.8629x over previous
//
#include <hip/hip_runtime.h>
#include <hip/hip_bf16.h>

typedef __bf16 bf16x8 __attribute__((ext_vector_type(8)));
typedef float  f32x4  __attribute__((ext_vector_type(4)));

// freqs[i] = 10000^(-i/16) = 10^(-i/4), i=0..7 (odd k-chunks scale by 1e-2)
__constant__ __device__ const float FREQ8[8] = {
    1.0f, 0.5623413251903491f, 0.31622776601683794f, 0.17782794100389228f,
    0.1f, 0.05623413251903491f, 0.031622776601683794f, 0.017782794100389228f };

// One wave = 64 points. D = W_tile(16e x 32d) * emb^T(32d x 16pt):
//   A-frag = W  (row=lane&15 -> e,     k=8*(lane>>4)+j -> d)
//   B-frag = emb (col=lane&15 -> point, k=8*(lane>>4)+j -> d)
//   D: col=lane&15 -> point, row=(lane>>4)*4+reg -> e  => 4 consecutive e per
//   lane = one 16B dwordx4 store. No LDS anywhere. Plain stores (nt regressed
//   2x in R4: bypassing L2 write-combining halves write BW on gfx950).
template<bool POW2>
__global__ __launch_bounds__(256) void relds_mfma(
    const float* __restrict__ pos,   // [B,N,3]
    const float* __restrict__ tim,   // [B,N]
    const float* __restrict__ W,     // [32,32] row-major W[e][d]
    const float* __restrict__ bias,  // [32]
    float* __restrict__ out_attn,    // f32 [P,32]
    float* __restrict__ out_emb,     // f32 [P,32]
    int N, int NN, int P, int logN)
{
    const int tid  = threadIdx.x;
    const int lane = tid & 63;
    const int wave = tid >> 6;
    const int row  = lane & 15;   // point-slot in B/D cols; e-row for A frag
    const int kb   = lane >> 4;   // k-chunk 0..3; also e-quad for D rows

    // ---- A fragments (W) + bias quads, once per block; L1/L2-resident ----
    bf16x8 Wf[2];
    f32x4  bq[2];
    #pragma unroll
    for (int n = 0; n < 2; ++n) {
        const int e = n * 16 + row;
        const float4 wA = *reinterpret_cast<const float4*>(W + e * 32 + kb * 8);
        const float4 wB = *reinterpret_cast<const float4*>(W + e * 32 + kb * 8 + 4);
        Wf[n][0] = (__bf16)wA.x; Wf[n][1] = (__bf16)wA.y;
        Wf[n][2] = (__bf16)wA.z; Wf[n][3] = (__bf16)wA.w;
        Wf[n][4] = (__bf16)wB.x; Wf[n][5] = (__bf16)wB.y;
        Wf[n][6] = (__bf16)wB.z; Wf[n][7] = (__bf16)wB.w;
        const float4 bb = *reinterpret_cast<const float4*>(bias + n * 16 + kb * 4);
        bq[n][0] = bb.x; bq[n][1] = bb.y; bq[n][2] = bb.z; bq[n][3] = bb.w;
    }

    const int wbase = blockIdx.x * 256 + wave * 64;
    if (wbase >= P) return;

    // lane-uniform angle constants: d = kb*8+j; odd chunk -> freqs*1e-2; kb>=2 -> cos
    constexpr float INV2PI = 0.15915494309189535f;
    const float premul = INV2PI * ((kb & 1) ? 0.01f : 1.0f);
    const float qoff   = (kb >= 2) ? 0.25f : 0.0f;   // cos(z) = sin(z + 1/4 rev)

    f32x4 acc[4][2];
    #pragma unroll
    for (int t = 0; t < 4; ++t)
        #pragma unroll
        for (int n = 0; n < 2; ++n) acc[t][n] = bq[n];

    #pragma unroll
    for (int t = 0; t < 4; ++t) {
        const int q  = wbase + t * 16 + row;
        const int qc = (q < P) ? q : (P - 1);
        int in_n, in_m;
        if (POW2) {
            in_n = qc >> logN;
            in_m = ((qc >> (2 * logN)) << logN) | (qc & (N - 1));
        } else {
            const int b_ = qc / NN; const int r_ = qc - b_ * NN;
            const int n_ = r_ / N;  const int m_ = r_ - n_ * N;
            in_n = b_ * N + n_;     in_m = b_ * N + m_;
        }
        const float dx = pos[in_n * 3 + 0] - pos[in_m * 3 + 0];
        const float dy = pos[in_n * 3 + 1] - pos[in_m * 3 + 1];
        const float dz = pos[in_n * 3 + 2] - pos[in_m * 3 + 2];
        const float dt = (tim[in_n] - tim[in_m]) * 18.0f;  // TIME_SCALE
        const float ds2 = dx * dx + dy * dy + dz * dz - dt * dt;
        const float d   = copysignf(sqrtf(fabsf(ds2)), ds2);
        const float x   = 1024.0f * fminf(4.0f, fmaxf(-4.0f, d));
        const float xr  = x * premul;   // revolutions, pre-scaled per k-chunk

        float v[8];
        #pragma unroll
        for (int j = 0; j < 8; ++j) {
            float rr = fmaf(xr, FREQ8[j], qoff);
            rr -= floorf(rr);
            v[j] = __builtin_amdgcn_sinf(rr);
        }

        if (q < P) {  // emb out: lane owns dims kb*8..kb*8+7 of point q
            float* ep = out_emb + (size_t)q * 32 + kb * 8;
            f32x4 e0 = { v[0], v[1], v[2], v[3] };
            f32x4 e1 = { v[4], v[5], v[6], v[7] };
            reinterpret_cast<f32x4*>(ep)[0] = e0;
            reinterpret_cast<f32x4*>(ep)[1] = e1;
        }

        bf16x8 Af;
        #pragma unroll
        for (int j = 0; j < 8; ++j) Af[j] = (__bf16)v[j];
        acc[t][0] = __builtin_amdgcn_mfma_f32_16x16x32_bf16(Wf[0], Af, acc[t][0], 0, 0, 0);
        acc[t][1] = __builtin_amdgcn_mfma_f32_16x16x32_bf16(Wf[1], Af, acc[t][1], 0, 0, 0);
    }

    // ---- rel_attn stores: D col=lane&15 -> point; e = n*16 + kb*4 + r ----
    #pragma unroll
    for (int t = 0; t < 4; ++t) {
        const int q = wbase + t * 16 + row;
        if (q < P) {
            float* ap = out_attn + (size_t)q * 32 + kb * 4;
            *reinterpret_cast<f32x4*>(ap)      = acc[t][0];  // e = kb*4 .. +3
            *reinterpret_cast<f32x4*>(ap + 16) = acc[t][1];  // e = 16 + kb*4 .. +3
        }
    }
}

extern "C" void kernel_launch(void* const* d_in, const int* in_sizes, int n_in,
                              void* d_out, int out_size, void* d_ws, size_t ws_size,
                              hipStream_t stream) {
    const float* pos  = (const float*)d_in[0];
    const float* tim  = (const float*)d_in[1];
    const float* W    = (const float*)d_in[2];
    const float* bias = (const float*)d_in[3];

    const int BN = in_sizes[1];          // B*N
    const int P  = out_size / 64;        // B*N*N
    const int N  = P / BN;
    const int NN = N * N;

    int logN = 0;
    while ((1 << logN) < N) ++logN;
    const bool pow2 = ((1 << logN) == N);

    float* out_attn = (float*)d_out;
    float* out_emb  = out_attn + (size_t)out_size / 2;

    const int grid = (P + 255) / 256;
    if (pow2)
        relds_mfma<true><<<grid, 256, 0, stream>>>(pos, tim, W, bias, out_attn, out_emb, N, NN, P, logN);
    else
        relds_mfma<false><<<grid, 256, 0, stream>>>(pos, tim, W, bias, out_attn, out_emb, N, NN, P, logN);
}

// Round 6
// 107.635 us; speedup vs baseline: 1.8871x; 1.0130x over previous
//
#include <hip/hip_runtime.h>
#include <hip/hip_bf16.h>

typedef __bf16 bf16x8 __attribute__((ext_vector_type(8)));
typedef float  f32x4  __attribute__((ext_vector_type(4)));

// freqs[i] = 10000^(-i/16) = 10^(-i/4), i=0..7 (odd k-chunks scale by 1e-2)
__constant__ __device__ const float FREQ8[8] = {
    1.0f, 0.5623413251903491f, 0.31622776601683794f, 0.17782794100389228f,
    0.1f, 0.05623413251903491f, 0.031622776601683794f, 0.017782794100389228f };

// One wave = 64 points. D = W_tile(16e x 32d) * emb^T(32d x 16pt):
//   A-frag = W   (row=lane&15 -> e,     k=8*(lane>>4)+j -> d)
//   B-frag = emb (col=lane&15 -> point, k=8*(lane>>4)+j -> d)
//   D: col=lane&15 -> point, row=(lane>>4)*4+reg -> e => one 16B store per n.
// Per-t attn stores: acc live range = 8 VGPRs (was 32), stores spread through
// the wave's life. launch_bounds(256,5) caps VGPR<=102 -> 5 waves/SIMD for
// more writes in flight (drain-throttle theory). Plain stores (nt = 2x slower,
// R4). No LDS anywhere.
template<bool POW2>
__global__ __launch_bounds__(256, 5) void relds_mfma(
    const float* __restrict__ pos,   // [B,N,3]
    const float* __restrict__ tim,   // [B,N]
    const float* __restrict__ W,     // [32,32] row-major W[e][d]
    const float* __restrict__ bias,  // [32]
    float* __restrict__ out_attn,    // f32 [P,32]
    float* __restrict__ out_emb,     // f32 [P,32]
    int N, int NN, int P, int logN)
{
    const int tid  = threadIdx.x;
    const int lane = tid & 63;
    const int wave = tid >> 6;
    const int row  = lane & 15;   // point-slot in B/D cols; e-row for A frag
    const int kb   = lane >> 4;   // k-chunk 0..3; also e-quad for D rows

    // ---- A fragments (W) + bias quads, once per block; L1/L2-resident ----
    bf16x8 Wf[2];
    f32x4  bq[2];
    #pragma unroll
    for (int n = 0; n < 2; ++n) {
        const int e = n * 16 + row;
        const float4 wA = *reinterpret_cast<const float4*>(W + e * 32 + kb * 8);
        const float4 wB = *reinterpret_cast<const float4*>(W + e * 32 + kb * 8 + 4);
        Wf[n][0] = (__bf16)wA.x; Wf[n][1] = (__bf16)wA.y;
        Wf[n][2] = (__bf16)wA.z; Wf[n][3] = (__bf16)wA.w;
        Wf[n][4] = (__bf16)wB.x; Wf[n][5] = (__bf16)wB.y;
        Wf[n][6] = (__bf16)wB.z; Wf[n][7] = (__bf16)wB.w;
        const float4 bb = *reinterpret_cast<const float4*>(bias + n * 16 + kb * 4);
        bq[n][0] = bb.x; bq[n][1] = bb.y; bq[n][2] = bb.z; bq[n][3] = bb.w;
    }

    const int wbase = blockIdx.x * 256 + wave * 64;
    if (wbase >= P) return;

    // lane-uniform angle constants: d = kb*8+j; odd chunk -> freqs*1e-2; kb>=2 -> cos
    constexpr float INV2PI = 0.15915494309189535f;
    const float premul = INV2PI * ((kb & 1) ? 0.01f : 1.0f);
    const float qoff   = (kb >= 2) ? 0.25f : 0.0f;   // cos(z) = sin(z + 1/4 rev)

    #pragma unroll
    for (int t = 0; t < 4; ++t) {
        const int q  = wbase + t * 16 + row;
        const int qc = (q < P) ? q : (P - 1);
        int in_n, in_m;
        if (POW2) {
            in_n = qc >> logN;
            in_m = ((qc >> (2 * logN)) << logN) | (qc & (N - 1));
        } else {
            const int b_ = qc / NN; const int r_ = qc - b_ * NN;
            const int n_ = r_ / N;  const int m_ = r_ - n_ * N;
            in_n = b_ * N + n_;     in_m = b_ * N + m_;
        }
        const float dx = pos[in_n * 3 + 0] - pos[in_m * 3 + 0];
        const float dy = pos[in_n * 3 + 1] - pos[in_m * 3 + 1];
        const float dz = pos[in_n * 3 + 2] - pos[in_m * 3 + 2];
        const float dt = (tim[in_n] - tim[in_m]) * 18.0f;  // TIME_SCALE
        const float ds2 = dx * dx + dy * dy + dz * dz - dt * dt;
        const float d   = copysignf(sqrtf(fabsf(ds2)), ds2);
        const float x   = 1024.0f * fminf(4.0f, fmaxf(-4.0f, d));
        const float xr  = x * premul;   // revolutions, pre-scaled per k-chunk

        float v[8];
        #pragma unroll
        for (int j = 0; j < 8; ++j) {
            float rr = fmaf(xr, FREQ8[j], qoff);
            rr -= floorf(rr);
            v[j] = __builtin_amdgcn_sinf(rr);
        }

        if (q < P) {  // emb out: lane owns dims kb*8..kb*8+7 of point q
            float* ep = out_emb + (size_t)q * 32 + kb * 8;
            f32x4 e0 = { v[0], v[1], v[2], v[3] };
            f32x4 e1 = { v[4], v[5], v[6], v[7] };
            reinterpret_cast<f32x4*>(ep)[0] = e0;
            reinterpret_cast<f32x4*>(ep)[1] = e1;
        }

        bf16x8 Af;
        #pragma unroll
        for (int j = 0; j < 8; ++j) Af[j] = (__bf16)v[j];
        f32x4 acc0 = __builtin_amdgcn_mfma_f32_16x16x32_bf16(Wf[0], Af, bq[0], 0, 0, 0);
        f32x4 acc1 = __builtin_amdgcn_mfma_f32_16x16x32_bf16(Wf[1], Af, bq[1], 0, 0, 0);

        // attn out for this tile: D col=lane&15 -> point; e = n*16 + kb*4 + r
        if (q < P) {
            float* ap = out_attn + (size_t)q * 32 + kb * 4;
            *reinterpret_cast<f32x4*>(ap)      = acc0;  // e = kb*4 .. +3
            *reinterpret_cast<f32x4*>(ap + 16) = acc1;  // e = 16 + kb*4 .. +3
        }
    }
}

extern "C" void kernel_launch(void* const* d_in, const int* in_sizes, int n_in,
                              void* d_out, int out_size, void* d_ws, size_t ws_size,
                              hipStream_t stream) {
    const float* pos  = (const float*)d_in[0];
    const float* tim  = (const float*)d_in[1];
    const float* W    = (const float*)d_in[2];
    const float* bias = (const float*)d_in[3];

    const int BN = in_sizes[1];          // B*N
    const int P  = out_size / 64;        // B*N*N
    const int N  = P / BN;
    const int NN = N * N;

    int logN = 0;
    while ((1 << logN) < N) ++logN;
    const bool pow2 = ((1 << logN) == N);

    float* out_attn = (float*)d_out;
    float* out_emb  = out_attn + (size_t)out_size / 2;

    const int grid = (P + 255) / 256;
    if (pow2)
        relds_mfma<true><<<grid, 256, 0, stream>>>(pos, tim, W, bias, out_attn, out_emb, N, NN, P, logN);
    else
        relds_mfma<false><<<grid, 256, 0, stream>>>(pos, tim, W, bias, out_attn, out_emb, N, NN, P, logN);
}